// Round 12
// baseline (5863.967 us; speedup 1.0000x reference)
//
#include <hip/hip_runtime.h>
#include <hip/hip_bf16.h>
#include <cstdint>
#include <cstddef>

using bf16 = __hip_bfloat16;

typedef __attribute__((ext_vector_type(8))) short short8;   // bf16x8 MFMA A/B frag
typedef __attribute__((ext_vector_type(4))) float f32x4;    // MFMA C/D frag
typedef __attribute__((ext_vector_type(4))) unsigned short us4;

static constexpr int Bb = 4, Ss = 2048, Hh = 2048, Ii = 8192, Gg = 128;
static constexpr int Mm = Bb * Ss;   // 8192 tokens

#define MEMFENCE() asm volatile("" ::: "memory")
#define BARRIER() do { MEMFENCE(); __builtin_amdgcn_s_barrier(); MEMFENCE(); } while (0)

// ---------------------------------------------------------------------------
// 1-bit group quantization: wq = sign(w) * mean(|w|) per contiguous 128-group.
// ---------------------------------------------------------------------------
__global__ void quant_onebit(const float* __restrict__ w, bf16* __restrict__ wq,
                             int ngroups) {
  int gid = blockIdx.x * 4 + (threadIdx.x >> 6);
  if (gid >= ngroups) return;
  int lane = threadIdx.x & 63;
  size_t base = (size_t)gid * Gg + (size_t)lane * 2;
  float2 v = *(const float2*)(w + base);
  float s = fabsf(v.x) + fabsf(v.y);
#pragma unroll
  for (int m = 32; m >= 1; m >>= 1) s += __shfl_xor(s, m);
  float scale = s * (1.0f / 128.0f);
  float q0 = (v.x > 0.f) ? scale : ((v.x < 0.f) ? -scale : 0.f);
  float q1 = (v.y > 0.f) ? scale : ((v.y < 0.f) ? -scale : 0.f);
  unsigned int p =
      (unsigned int)__builtin_bit_cast(unsigned short, __float2bfloat16(q0)) |
      ((unsigned int)__builtin_bit_cast(unsigned short, __float2bfloat16(q1)) << 16);
  *(unsigned int*)(wq + base) = p;
}

__global__ void cast_f32_bf16(const float* __restrict__ in, bf16* __restrict__ out,
                              size_t n4) {
  size_t i = (size_t)blockIdx.x * blockDim.x + threadIdx.x;
  if (i >= n4) return;
  float4 v = *(const float4*)(in + i * 4);
  us4 o;
  o.x = __builtin_bit_cast(unsigned short, __float2bfloat16(v.x));
  o.y = __builtin_bit_cast(unsigned short, __float2bfloat16(v.y));
  o.z = __builtin_bit_cast(unsigned short, __float2bfloat16(v.z));
  o.w = __builtin_bit_cast(unsigned short, __float2bfloat16(v.w));
  *(us4*)(out + i * 4) = o;
}

// ---------------------------------------------------------------------------
// 256-row GEMM, 16x16x32 MFMA, BK=32, 2-deep dbuf = 64 KiB LDS
// -> 2 BLOCKS/CU (R12's lever; all prior rounds ran 1 block/CU and the
// intra-block LDS<->MFMA serialization capped MfmaUtil at ~47%).
// Per tile t: {vmcnt(0); barrier; [read fb+fa0-3; stage A(t+1); 16 MFMA];
// barrier; [read fa4-7; stage B(t+1); 16 MFMA]}. Stages issued mid-tile
// land ~1500 cyc before the next entry wait. Race audit in round notes.
// 64B-row XOR slot-swizzle (0 conflicts, 5 rounds), chunked-N XCD mapping.
// DUAL: fused gate/up (two 128-col B panels) + silu epilogue -> bf16.
// ---------------------------------------------------------------------------
__device__ __forceinline__ void gload16(const bf16* g, char* l) {
  __builtin_amdgcn_global_load_lds(
      (const __attribute__((address_space(1))) void*)g,
      (__attribute__((address_space(3))) void*)l, 16, 0, 0);
}

// Swizzled frag read: row stride 64 B (4 x 16 B slots), phys slot = s ^ (row>>1)&3.
__device__ __forceinline__ short8 lfrag(const char* part, int row, int s) {
  return *(const short8*)(part + row * 64 + (((s ^ (row >> 1)) & 3) << 4));
}

template <bool DUAL>
__global__ __launch_bounds__(512, 4)
void gemm_bt8(const bf16* __restrict__ A,   // [M,K]
              const bf16* __restrict__ B0,  // [N,K]
              const bf16* __restrict__ B1,  // [N,K] (DUAL)
              bf16* __restrict__ OutBf,     // [M,N] (DUAL)
              float* __restrict__ OutF,     // [M,N] (!DUAL)
              int M, int N, int K) {
  constexpr int BM = 256, BN = DUAL ? 128 : 256;
  constexpr int NF = DUAL ? 2 : 4;        // n-frags per wave (per matrix)
  // LDS: buf[2] x (A 16K + B 16K) = 65536 B
  extern __shared__ char smem[];

  const int tid = threadIdx.x;
  const int wid = tid >> 6;               // 0..7
  const int lane = tid & 63;
  const int wr = wid >> 2;                // 0..1 row half
  const int wc = wid & 3;                 // 0..3 col quarter
  const int lrow = lane & 15;
  const int ks = lane >> 4;               // 16B slot 0..3 within 64B k-row

  // ---- locality mapping: XCD-bijective, then chunk N (CN=8 n-blocks x all
  // m-blocks per chunk). nbx % 8 == 0 (64 dual, 8 single).
  const int nbx = N / BN;
  const int nbm = M / BM;
  const int nwg = (int)gridDim.x;
  const int cpx = nwg >> 3;
  const int wg = (int)blockIdx.x;
  const int L = (wg & 7) * cpx + (wg >> 3);
  constexpr int CN = 8;
  const int chunk = L / (nbm * CN);
  const int within = L % (nbm * CN);
  const int m0 = (within / CN) * BM;
  const int n0 = (chunk * CN + (within % CN)) * BN;

  const int NT = K / 32;                  // 64 (GEMM1) / 256 (GEMM2)

  // ---- staging: dest linear (wave base + lane*16); source slot
  // inverse-swizzled so linear write + swizzled read compose to identity.
  const int srow = tid >> 2;                          // 0..127
  const int slog8 = (((tid & 3) ^ ((tid >> 3) & 3)) << 3);
  const bf16* pA0 = A + (size_t)(m0 + srow) * K + slog8;
  const bf16* pA1 = pA0 + (size_t)128 * K;
  const bf16* pB0 = B0 + (size_t)(n0 + srow) * K + slog8;
  const bf16* pB1 = DUAL ? (B1 + (size_t)(n0 + srow) * K + slog8)
                         : (pB0 + (size_t)128 * K);
  const int dA = wid * 1024;

  auto stageA = [&](int t) {              // 2 loads: A rows 0..255, 32 k
    char* b = smem + (size_t)(t & 1) * 32768;
    const int koff = t * 32;
    gload16(pA0 + koff, b + dA);
    gload16(pA1 + koff, b + 8192 + dA);
  };
  auto stageB = [&](int t) {              // 2 loads: B panel(s), 32 k
    char* b = smem + (size_t)(t & 1) * 32768 + 16384;
    const int koff = t * 32;
    gload16(pB0 + koff, b + dA);
    gload16(pB1 + koff, b + 8192 + dA);
  };

  const f32x4 vzero = {0.f, 0.f, 0.f, 0.f};
  f32x4 acc0[8][NF];
  f32x4 acc1[DUAL ? 8 : 1][NF];
#pragma unroll
  for (int mf = 0; mf < 8; ++mf)
#pragma unroll
    for (int nf = 0; nf < NF; ++nf) {
      acc0[mf][nf] = vzero;
      if constexpr (DUAL) acc1[mf][nf] = vzero;
    }

  // ---- prologue: stage tile0 (4 loads)
  stageA(0); stageB(0);

  short8 fa[4], fb0[NF], fb1[DUAL ? NF : 1];

  for (int t = 0; t < NT; ++t) {
    // entry: retire tile t's 4 loads (issued mid tile t-1; prologue for t=0)
    asm volatile("s_waitcnt vmcnt(0)" ::: "memory");
    BARRIER();
    const char* Ap = smem + (size_t)(t & 1) * 32768;
    const char* Bp = Ap + 16384;

    // ===== sub-phase 0: read B + A[mf0-3]; stage A(t+1); 16 MFMA
    if constexpr (DUAL) {
#pragma unroll
      for (int nf = 0; nf < 2; ++nf) {
        fb0[nf] = lfrag(Bp, wc * 32 + nf * 16 + lrow, ks);
        fb1[nf] = lfrag(Bp + 8192, wc * 32 + nf * 16 + lrow, ks);
      }
    } else {
#pragma unroll
      for (int nf = 0; nf < 4; ++nf)
        fb0[nf] = lfrag(Bp, wc * 64 + nf * 16 + lrow, ks);
    }
#pragma unroll
    for (int i = 0; i < 4; ++i)
      fa[i] = lfrag(Ap, wr * 128 + i * 16 + lrow, ks);
    if (t + 1 < NT) stageA(t + 1);
    __builtin_amdgcn_s_setprio(1);
#pragma unroll
    for (int i = 0; i < 4; ++i)
#pragma unroll
      for (int nf = 0; nf < NF; ++nf) {
        acc0[i][nf] = __builtin_amdgcn_mfma_f32_16x16x32_bf16(
            fa[i], fb0[nf], acc0[i][nf], 0, 0, 0);
        if constexpr (DUAL)
          acc1[i][nf] = __builtin_amdgcn_mfma_f32_16x16x32_bf16(
              fa[i], fb1[nf], acc1[i][nf], 0, 0, 0);
      }
    __builtin_amdgcn_s_setprio(0);
    BARRIER();

    // ===== sub-phase 1: read A[mf4-7] (B reused); stage B(t+1); 16 MFMA
#pragma unroll
    for (int i = 0; i < 4; ++i)
      fa[i] = lfrag(Ap, wr * 128 + 64 + i * 16 + lrow, ks);
    if (t + 1 < NT) stageB(t + 1);
    __builtin_amdgcn_s_setprio(1);
#pragma unroll
    for (int i = 0; i < 4; ++i)
#pragma unroll
      for (int nf = 0; nf < NF; ++nf) {
        acc0[4 + i][nf] = __builtin_amdgcn_mfma_f32_16x16x32_bf16(
            fa[i], fb0[nf], acc0[4 + i][nf], 0, 0, 0);
        if constexpr (DUAL)
          acc1[4 + i][nf] = __builtin_amdgcn_mfma_f32_16x16x32_bf16(
              fa[i], fb1[nf], acc1[4 + i][nf], 0, 0, 0);
      }
    __builtin_amdgcn_s_setprio(0);
  }

  // ---- epilogue: C/D layout col=lane&15, row=(lane>>4)*4+j
  const int crow0 = (lane >> 4) * 4;
  const int ccol = lane & 15;
#pragma unroll
  for (int mf = 0; mf < 8; ++mf)
#pragma unroll
    for (int nf = 0; nf < NF; ++nf)
#pragma unroll
      for (int j = 0; j < 4; ++j) {
        const int row = m0 + wr * 128 + mf * 16 + crow0 + j;
        if constexpr (DUAL) {
          const int col = n0 + wc * 32 + nf * 16 + ccol;
          float g = acc0[mf][nf][j];
          float u = acc1[mf][nf][j];
          OutBf[(size_t)row * N + col] =
              __float2bfloat16(g / (1.0f + expf(-g)) * u);
        } else {
          const int col = n0 + wc * 64 + nf * 16 + ccol;
          OutF[(size_t)row * N + col] = acc0[mf][nf][j];
        }
      }
}

// ---------------------------------------------------------------------------
extern "C" void kernel_launch(void* const* d_in, const int* in_sizes, int n_in,
                              void* d_out, int out_size, void* d_ws, size_t ws_size,
                              hipStream_t stream) {
  const float* x = (const float*)d_in[0];
  const float* wg = (const float*)d_in[1];
  const float* wu = (const float*)d_in[2];
  const float* wd = (const float*)d_in[3];
  float* out = (float*)d_out;

  char* ws = (char*)d_ws;
  bf16* xq = (bf16*)(ws + 0);
  bf16* wgq = (bf16*)(ws + (size_t)33554432);
  bf16* wuq = (bf16*)(ws + (size_t)67108864);
  bf16* hbuf = (bf16*)(ws + (size_t)100663296);
  bf16* wdq = xq;  // xq dead after GEMM1

  auto* kDual = gemm_bt8<true>;
  auto* kSingle = gemm_bt8<false>;
  (void)hipFuncSetAttribute((const void*)kDual,
                            hipFuncAttributeMaxDynamicSharedMemorySize, 65536);
  (void)hipFuncSetAttribute((const void*)kSingle,
                            hipFuncAttributeMaxDynamicSharedMemorySize, 65536);

  const int ngW = (Ii * Hh) / Gg;
  quant_onebit<<<ngW / 4, 256, 0, stream>>>(wg, wgq, ngW);
  quant_onebit<<<ngW / 4, 256, 0, stream>>>(wu, wuq, ngW);

  const size_t n4 = (size_t)Mm * Hh / 4;
  cast_f32_bf16<<<(unsigned)((n4 + 255) / 256), 256, 0, stream>>>(x, xq, n4);

  // GEMM1 fused: h = silu(x@wgq^T) * (x@wuq^T)  [M=8192, N=8192, K=2048]
  kDual<<<(Mm / 256) * (Ii / 128), 512, 65536, stream>>>(
      xq, wgq, wuq, hbuf, nullptr, Mm, Ii, Hh);

  quant_onebit<<<ngW / 4, 256, 0, stream>>>(wd, wdq, ngW);

  // GEMM2: out = h @ wdq^T  [M=8192, N=2048, K=8192]
  kSingle<<<(Mm / 256) * (Hh / 256), 512, 65536, stream>>>(
      hbuf, wdq, nullptr, nullptr, out, Mm, Hh, Ii);
}

// Round 13
// 888.000 us; speedup vs baseline: 6.6036x; 6.6036x over previous
//
#include <hip/hip_runtime.h>
#include <hip/hip_bf16.h>
#include <cstdint>
#include <cstddef>

using bf16 = __hip_bfloat16;

typedef __attribute__((ext_vector_type(8))) short short8;   // bf16x8 MFMA A/B frag
typedef __attribute__((ext_vector_type(4))) float f32x4;    // MFMA C/D frag
typedef __attribute__((ext_vector_type(4))) unsigned short us4;

static constexpr int Bb = 4, Ss = 2048, Hh = 2048, Ii = 8192, Gg = 128;
static constexpr int Mm = Bb * Ss;   // 8192 tokens

#define MEMFENCE() asm volatile("" ::: "memory")
#define BARRIER() do { MEMFENCE(); __builtin_amdgcn_s_barrier(); MEMFENCE(); } while (0)

// ---------------------------------------------------------------------------
// 1-bit group quantization: wq = sign(w) * mean(|w|) per contiguous 128-group.
// ---------------------------------------------------------------------------
__global__ void quant_onebit(const float* __restrict__ w, bf16* __restrict__ wq,
                             int ngroups) {
  int gid = blockIdx.x * 4 + (threadIdx.x >> 6);
  if (gid >= ngroups) return;
  int lane = threadIdx.x & 63;
  size_t base = (size_t)gid * Gg + (size_t)lane * 2;
  float2 v = *(const float2*)(w + base);
  float s = fabsf(v.x) + fabsf(v.y);
#pragma unroll
  for (int m = 32; m >= 1; m >>= 1) s += __shfl_xor(s, m);
  float scale = s * (1.0f / 128.0f);
  float q0 = (v.x > 0.f) ? scale : ((v.x < 0.f) ? -scale : 0.f);
  float q1 = (v.y > 0.f) ? scale : ((v.y < 0.f) ? -scale : 0.f);
  unsigned int p =
      (unsigned int)__builtin_bit_cast(unsigned short, __float2bfloat16(q0)) |
      ((unsigned int)__builtin_bit_cast(unsigned short, __float2bfloat16(q1)) << 16);
  *(unsigned int*)(wq + base) = p;
}

__global__ void cast_f32_bf16(const float* __restrict__ in, bf16* __restrict__ out,
                              size_t n4) {
  size_t i = (size_t)blockIdx.x * blockDim.x + threadIdx.x;
  if (i >= n4) return;
  float4 v = *(const float4*)(in + i * 4);
  us4 o;
  o.x = __builtin_bit_cast(unsigned short, __float2bfloat16(v.x));
  o.y = __builtin_bit_cast(unsigned short, __float2bfloat16(v.y));
  o.z = __builtin_bit_cast(unsigned short, __float2bfloat16(v.z));
  o.w = __builtin_bit_cast(unsigned short, __float2bfloat16(v.w));
  *(us4*)(out + i * 4) = o;
}

// ---------------------------------------------------------------------------
// 256-row GEMM, 16x16x32 MFMA, BK=32, 2-deep dbuf = 64 KiB LDS -> 2 blocks/CU.
// R13 = R12 with __launch_bounds__(512,2): R12's (512,4) capped VGPR at 64
// and spilled the 128-VGPR accumulator set to scratch (FETCH 0.39->7.7 GB,
// MfmaUtil 6.5%). Occupancy DID double (46%) -> mechanism works; retest
// without the register cap (compiler ~92 VGPR, 128-granule -> 16 waves/CU).
// Per tile t: {vmcnt(0); barrier; [read fb+fa0-3; stage A(t+1); 16 MFMA];
// barrier; [read fa4-7; stage B(t+1); 16 MFMA]}.
// 64B-row XOR slot-swizzle (0 conflicts, 6 rounds), chunked-N XCD mapping.
// DUAL: fused gate/up (two 128-col B panels) + silu epilogue -> bf16.
// ---------------------------------------------------------------------------
__device__ __forceinline__ void gload16(const bf16* g, char* l) {
  __builtin_amdgcn_global_load_lds(
      (const __attribute__((address_space(1))) void*)g,
      (__attribute__((address_space(3))) void*)l, 16, 0, 0);
}

// Swizzled frag read: row stride 64 B (4 x 16 B slots), phys slot = s ^ (row>>1)&3.
__device__ __forceinline__ short8 lfrag(const char* part, int row, int s) {
  return *(const short8*)(part + row * 64 + (((s ^ (row >> 1)) & 3) << 4));
}

template <bool DUAL>
__global__ __launch_bounds__(512, 2)
void gemm_bt8(const bf16* __restrict__ A,   // [M,K]
              const bf16* __restrict__ B0,  // [N,K]
              const bf16* __restrict__ B1,  // [N,K] (DUAL)
              bf16* __restrict__ OutBf,     // [M,N] (DUAL)
              float* __restrict__ OutF,     // [M,N] (!DUAL)
              int M, int N, int K) {
  constexpr int BM = 256, BN = DUAL ? 128 : 256;
  constexpr int NF = DUAL ? 2 : 4;        // n-frags per wave (per matrix)
  // LDS: buf[2] x (A 16K + B 16K) = 65536 B
  extern __shared__ char smem[];

  const int tid = threadIdx.x;
  const int wid = tid >> 6;               // 0..7
  const int lane = tid & 63;
  const int wr = wid >> 2;                // 0..1 row half
  const int wc = wid & 3;                 // 0..3 col quarter
  const int lrow = lane & 15;
  const int ks = lane >> 4;               // 16B slot 0..3 within 64B k-row

  // ---- locality mapping: XCD-bijective, then chunk N (CN=8 n-blocks x all
  // m-blocks per chunk). nbx % 8 == 0 (64 dual, 8 single).
  const int nbx = N / BN;
  const int nbm = M / BM;
  const int nwg = (int)gridDim.x;
  const int cpx = nwg >> 3;
  const int wg = (int)blockIdx.x;
  const int L = (wg & 7) * cpx + (wg >> 3);
  constexpr int CN = 8;
  const int chunk = L / (nbm * CN);
  const int within = L % (nbm * CN);
  const int m0 = (within / CN) * BM;
  const int n0 = (chunk * CN + (within % CN)) * BN;

  const int NT = K / 32;                  // 64 (GEMM1) / 256 (GEMM2)

  // ---- staging: dest linear (wave base + lane*16); source slot
  // inverse-swizzled so linear write + swizzled read compose to identity.
  const int srow = tid >> 2;                          // 0..127
  const int slog8 = (((tid & 3) ^ ((tid >> 3) & 3)) << 3);
  const bf16* pA0 = A + (size_t)(m0 + srow) * K + slog8;
  const bf16* pA1 = pA0 + (size_t)128 * K;
  const bf16* pB0 = B0 + (size_t)(n0 + srow) * K + slog8;
  const bf16* pB1 = DUAL ? (B1 + (size_t)(n0 + srow) * K + slog8)
                         : (pB0 + (size_t)128 * K);
  const int dA = wid * 1024;

  auto stageA = [&](int t) {              // 2 loads: A rows 0..255, 32 k
    char* b = smem + (size_t)(t & 1) * 32768;
    const int koff = t * 32;
    gload16(pA0 + koff, b + dA);
    gload16(pA1 + koff, b + 8192 + dA);
  };
  auto stageB = [&](int t) {              // 2 loads: B panel(s), 32 k
    char* b = smem + (size_t)(t & 1) * 32768 + 16384;
    const int koff = t * 32;
    gload16(pB0 + koff, b + dA);
    gload16(pB1 + koff, b + 8192 + dA);
  };

  const f32x4 vzero = {0.f, 0.f, 0.f, 0.f};
  f32x4 acc0[8][NF];
  f32x4 acc1[DUAL ? 8 : 1][NF];
#pragma unroll
  for (int mf = 0; mf < 8; ++mf)
#pragma unroll
    for (int nf = 0; nf < NF; ++nf) {
      acc0[mf][nf] = vzero;
      if constexpr (DUAL) acc1[mf][nf] = vzero;
    }

  // ---- prologue: stage tile0 (4 loads)
  stageA(0); stageB(0);

  short8 fa[4], fb0[NF], fb1[DUAL ? NF : 1];

  for (int t = 0; t < NT; ++t) {
    // entry: retire tile t's 4 loads (issued mid tile t-1; prologue for t=0)
    asm volatile("s_waitcnt vmcnt(0)" ::: "memory");
    BARRIER();
    const char* Ap = smem + (size_t)(t & 1) * 32768;
    const char* Bp = Ap + 16384;

    // ===== sub-phase 0: read B + A[mf0-3]; stage A(t+1); 16 MFMA
    if constexpr (DUAL) {
#pragma unroll
      for (int nf = 0; nf < 2; ++nf) {
        fb0[nf] = lfrag(Bp, wc * 32 + nf * 16 + lrow, ks);
        fb1[nf] = lfrag(Bp + 8192, wc * 32 + nf * 16 + lrow, ks);
      }
    } else {
#pragma unroll
      for (int nf = 0; nf < 4; ++nf)
        fb0[nf] = lfrag(Bp, wc * 64 + nf * 16 + lrow, ks);
    }
#pragma unroll
    for (int i = 0; i < 4; ++i)
      fa[i] = lfrag(Ap, wr * 128 + i * 16 + lrow, ks);
    if (t + 1 < NT) stageA(t + 1);
    __builtin_amdgcn_s_setprio(1);
#pragma unroll
    for (int i = 0; i < 4; ++i)
#pragma unroll
      for (int nf = 0; nf < NF; ++nf) {
        acc0[i][nf] = __builtin_amdgcn_mfma_f32_16x16x32_bf16(
            fa[i], fb0[nf], acc0[i][nf], 0, 0, 0);
        if constexpr (DUAL)
          acc1[i][nf] = __builtin_amdgcn_mfma_f32_16x16x32_bf16(
              fa[i], fb1[nf], acc1[i][nf], 0, 0, 0);
      }
    __builtin_amdgcn_s_setprio(0);
    BARRIER();

    // ===== sub-phase 1: read A[mf4-7] (B reused); stage B(t+1); 16 MFMA
#pragma unroll
    for (int i = 0; i < 4; ++i)
      fa[i] = lfrag(Ap, wr * 128 + 64 + i * 16 + lrow, ks);
    if (t + 1 < NT) stageB(t + 1);
    __builtin_amdgcn_s_setprio(1);
#pragma unroll
    for (int i = 0; i < 4; ++i)
#pragma unroll
      for (int nf = 0; nf < NF; ++nf) {
        acc0[4 + i][nf] = __builtin_amdgcn_mfma_f32_16x16x32_bf16(
            fa[i], fb0[nf], acc0[4 + i][nf], 0, 0, 0);
        if constexpr (DUAL)
          acc1[4 + i][nf] = __builtin_amdgcn_mfma_f32_16x16x32_bf16(
              fa[i], fb1[nf], acc1[4 + i][nf], 0, 0, 0);
      }
    __builtin_amdgcn_s_setprio(0);
  }

  // ---- epilogue: C/D layout col=lane&15, row=(lane>>4)*4+j
  const int crow0 = (lane >> 4) * 4;
  const int ccol = lane & 15;
#pragma unroll
  for (int mf = 0; mf < 8; ++mf)
#pragma unroll
    for (int nf = 0; nf < NF; ++nf)
#pragma unroll
      for (int j = 0; j < 4; ++j) {
        const int row = m0 + wr * 128 + mf * 16 + crow0 + j;
        if constexpr (DUAL) {
          const int col = n0 + wc * 32 + nf * 16 + ccol;
          float g = acc0[mf][nf][j];
          float u = acc1[mf][nf][j];
          OutBf[(size_t)row * N + col] =
              __float2bfloat16(g / (1.0f + expf(-g)) * u);
        } else {
          const int col = n0 + wc * 64 + nf * 16 + ccol;
          OutF[(size_t)row * N + col] = acc0[mf][nf][j];
        }
      }
}

// ---------------------------------------------------------------------------
extern "C" void kernel_launch(void* const* d_in, const int* in_sizes, int n_in,
                              void* d_out, int out_size, void* d_ws, size_t ws_size,
                              hipStream_t stream) {
  const float* x = (const float*)d_in[0];
  const float* wg = (const float*)d_in[1];
  const float* wu = (const float*)d_in[2];
  const float* wd = (const float*)d_in[3];
  float* out = (float*)d_out;

  char* ws = (char*)d_ws;
  bf16* xq = (bf16*)(ws + 0);
  bf16* wgq = (bf16*)(ws + (size_t)33554432);
  bf16* wuq = (bf16*)(ws + (size_t)67108864);
  bf16* hbuf = (bf16*)(ws + (size_t)100663296);
  bf16* wdq = xq;  // xq dead after GEMM1

  auto* kDual = gemm_bt8<true>;
  auto* kSingle = gemm_bt8<false>;
  (void)hipFuncSetAttribute((const void*)kDual,
                            hipFuncAttributeMaxDynamicSharedMemorySize, 65536);
  (void)hipFuncSetAttribute((const void*)kSingle,
                            hipFuncAttributeMaxDynamicSharedMemorySize, 65536);

  const int ngW = (Ii * Hh) / Gg;
  quant_onebit<<<ngW / 4, 256, 0, stream>>>(wg, wgq, ngW);
  quant_onebit<<<ngW / 4, 256, 0, stream>>>(wu, wuq, ngW);

  const size_t n4 = (size_t)Mm * Hh / 4;
  cast_f32_bf16<<<(unsigned)((n4 + 255) / 256), 256, 0, stream>>>(x, xq, n4);

  // GEMM1 fused: h = silu(x@wgq^T) * (x@wuq^T)  [M=8192, N=8192, K=2048]
  kDual<<<(Mm / 256) * (Ii / 128), 512, 65536, stream>>>(
      xq, wgq, wuq, hbuf, nullptr, Mm, Ii, Hh);

  quant_onebit<<<ngW / 4, 256, 0, stream>>>(wd, wdq, ngW);

  // GEMM2: out = h @ wdq^T  [M=8192, N=2048, K=8192]
  kSingle<<<(Mm / 256) * (Hh / 256), 512, 65536, stream>>>(
      hbuf, wdq, nullptr, nullptr, out, Mm, Hh, Ii);
}